// Round 5
// baseline (425.263 us; speedup 1.0000x reference)
//
#include <hip/hip_runtime.h>

// ---------------- problem constants ----------------
#define EE 200000
#define VV 50000
#define LN 128
#define KD 256     // 2*LN
#define SS 32
#define NN 1024    // SS*SS
#define CC 10
#define MUS 0.028125f   // MU/S = 0.9/32

typedef short short8_t __attribute__((ext_vector_type(8)));
typedef float f32x4 __attribute__((ext_vector_type(4)));

__device__ __forceinline__ unsigned short f32_to_bf16_rne(float f) {
    union { float f; unsigned u; } x; x.f = f;
    unsigned r = x.u + 0x7FFFu + ((x.u >> 16) & 1u);
    return (unsigned short)(r >> 16);
}

__device__ __forceinline__ float bf16_to_f32(unsigned short h) {
    union { unsigned u; float f; } x; x.u = ((unsigned)h) << 16; return x.f;
}

__device__ __forceinline__ float tanh_fast(float x) {
    float t = __builtin_amdgcn_exp2f(x * 2.885390081777927f);
    return 1.0f - 2.0f * __builtin_amdgcn_rcpf(t + 1.0f);
}

// Pade(3,2): x(27+x^2)/(27+9x^2). |err|<=0.023 for |x|<2; enters He scaled by
// MUS/deg <= 0.028 -> negligible vs 6.8e-2 threshold. (Validated R3.)
__device__ __forceinline__ float ptanh(float x) {
    float x2 = x * x;
    return x * (27.f + x2) * __builtin_amdgcn_rcpf(27.f + 9.f * x2);
}

__device__ __forceinline__ void load_lds16(const void* g, void* l) {
    __builtin_amdgcn_global_load_lds(
        (const __attribute__((address_space(1))) unsigned int*)g,
        (__attribute__((address_space(3))) unsigned int*)l,
        16, 0, 0);
}

// ---------------- K_prep: feat->bf16 | Wxi->bf16 permuted | bxiT | hist ----------------
// blocks [0,6250): featB; [6250,7274): WxiB; 7274: bxiT; [7275,8057): hist
__global__ void k_prep(const float* __restrict__ feat, unsigned short* __restrict__ featB,
                       const float* __restrict__ Wxi, unsigned short* __restrict__ WxiB,
                       const float* __restrict__ bxi, float* __restrict__ bxiT,
                       const int* __restrict__ Xn, int* __restrict__ cnt) {
    int b = blockIdx.x, tid = threadIdx.x;
    if (b < 6250) {
        int idx = b * 256 + tid;                       // VV*LN/4
        float4 v = ((const float4*)feat)[idx];
        ushort4 o;
        o.x = f32_to_bf16_rne(v.x); o.y = f32_to_bf16_rne(v.y);
        o.z = f32_to_bf16_rne(v.z); o.w = f32_to_bf16_rne(v.w);
        ((ushort4*)featB)[idx] = o;
    } else if (b < 7274) {
        int idx = (b - 6250) * 256 + tid;              // KD*NN
        int k = idx >> 10, ncol = idx & 1023;
        int np = ((ncol & 31) << 5) | (ncol >> 5);     // n' = j*32+i
        WxiB[((size_t)(k >> 3) * NN + np) * 8 + (k & 7)] = f32_to_bf16_rne(Wxi[idx]);
    } else if (b == 7274) {
        #pragma unroll
        for (int it = 0; it < 4; ++it) {
            int i = it * 256 + tid;
            bxiT[i] = bxi[(i & 31) * 32 + (i >> 5)];
        }
    } else {
        int e = (b - 7275) * 256 + tid;
        if (e < EE) atomicAdd(&cnt[Xn[e]], 1);
    }
}

// ---------------- K_scan: single-block exclusive scan of cnt -> rowptr, cursor ----------------
#define SCAN_C 49
__global__ void __launch_bounds__(1024) k_scan(const int* __restrict__ cnt,
                                               int* __restrict__ rowptr,
                                               int* __restrict__ cursor) {
    __shared__ int wsum[16];
    int tid = threadIdx.x;
    int base = tid * SCAN_C;
    int s = 0;
    for (int i = 0; i < SCAN_C; ++i) {
        int idx = base + i;
        if (idx < VV) s += cnt[idx];
    }
    int lane = tid & 63, wid = tid >> 6;
    int v = s;
    #pragma unroll
    for (int off = 1; off < 64; off <<= 1) {
        int t = __shfl_up(v, off);
        if (lane >= off) v += t;
    }
    if (lane == 63) wsum[wid] = v;
    __syncthreads();
    if (tid < 16) {
        int x = wsum[tid];
        #pragma unroll
        for (int off = 1; off < 16; off <<= 1) {
            int t = __shfl_up(x, off);
            if (tid >= off) x += t;
        }
        wsum[tid] = x;                                 // inclusive wave totals
    }
    __syncthreads();
    int run = v - s + (wid ? wsum[wid - 1] : 0);       // exclusive prefix
    for (int i = 0; i < SCAN_C; ++i) {
        int idx = base + i;
        if (idx < VV) {
            rowptr[idx] = run; cursor[idx] = run;
            run += cnt[idx];
        }
    }
    if (tid == 0) rowptr[VV] = EE;
}

__global__ void k_scatter(const int* __restrict__ Xn, int* __restrict__ cursor,
                          int* __restrict__ perm) {
    int e = blockIdx.x * 256 + threadIdx.x;
    if (e < EE) {
        int p = atomicAdd(&cursor[Xn[e]], 1);
        perm[p] = e;
    }
}

// ---------------- K_h1: H1[u] = cnt[u] * tanh(feat[u] @ Wrou + brou) ----------------
__global__ void k_h1(const float* __restrict__ feat, const float* __restrict__ Wrou,
                     const float* __restrict__ brou, const int* __restrict__ cnt,
                     float* __restrict__ H1) {
    int gid = blockIdx.x * 256 + threadIdx.x;          // VV*SS
    int u = gid >> 5, s = gid & 31;
    const float* fr = feat + (size_t)u * LN;
    float a = brou[s];
    #pragma unroll 8
    for (int k = 0; k < LN; ++k) a += fr[k] * Wrou[k * SS + s];
    H1[gid] = (float)cnt[u] * tanh_fast(a);
}

// ---------------- K4: He[e][i] = scale_e * sum_j ptanh(S[e][i,j]+bx) * h_e[j] ----------------
// wave = 32 edges x full N; B LDS-staged per block (2 chunks = 32 KB per iter)
__global__ void __launch_bounds__(256, 3)
k_edge_gemm(const unsigned short* __restrict__ featB, const unsigned short* __restrict__ WxiB,
            const int* __restrict__ Xn, const int* __restrict__ Xe,
            const float* __restrict__ dg, const float* __restrict__ bxiT,
            const int* __restrict__ perm, const float* __restrict__ H1,
            unsigned short* __restrict__ HeB) {
    __shared__ __align__(16) unsigned short Bs[2 * 8192];   // 32 KB: 2 chunk slots
    __shared__ float hs[128][33];                           // 16.9 KB
    __shared__ int   us[128], vs[128];
    __shared__ float scale_s[128];

    const int tid = threadIdx.x;
    const int eb = blockIdx.x * 128;

    if (tid < 128) {
        int p = eb + tid; if (p > EE - 1) p = EE - 1;
        int e0 = perm[p];
        us[tid] = Xn[e0]; vs[tid] = Xe[e0];
        scale_s[tid] = MUS / dg[e0];
    }
    __syncthreads();

    const int w = tid >> 6, lane = tid & 63;
    const int g = lane >> 4, l15 = lane & 15;
    const int row0 = w * 32;

    // A fragments, gathered once (64 VGPR)
    short8_t af[8][2];
    #pragma unroll
    for (int kk = 0; kk < 8; ++kk)
        #pragma unroll
        for (int mf = 0; mf < 2; ++mf) {
            int el = row0 + mf * 16 + l15;
            int node = (kk < 4) ? us[el] : vs[el];
            af[kk][mf] = *(const short8_t*)(featB + (size_t)node * LN + (kk & 3) * 32 + g * 8);
        }

    // stage h rows (coalesced)
    #pragma unroll
    for (int it = 0; it < 16; ++it) {
        int idx = it * 256 + tid;
        int el = idx >> 5, s = idx & 31;
        hs[el][s] = H1[us[el] * SS + s];
    }

    // staging source/dest (loop-invariant parts)
    // LDS 16B-unit L = w*512 + q*64 + lane ; slot = w>>1 ; kk4g = (w&1)*16+q*2+(lane>>5)
    const char* gsrc0 = (const char*)WxiB +
        ((size_t)(((w & 1) * 16 + (lane >> 5)) * 16384) + (w >> 1) * 512 + (lane & 31) * 16);
    char* ldst0 = (char*)Bs + w * 8192;
    const char* bbase = (const char*)Bs + (g * 512 + l15 * 16);

    f32x4 he[2][2];
    #pragma unroll
    for (int mf = 0; mf < 2; ++mf)
        #pragma unroll
        for (int f = 0; f < 2; ++f)
            he[mf][f] = (f32x4){0.f, 0.f, 0.f, 0.f};

    #pragma unroll 1
    for (int it = 0; it < 16; ++it) {
        __syncthreads();                                   // prev compute done
        const char* gs = gsrc0 + it * 1024;
        #pragma unroll
        for (int q = 0; q < 8; ++q)
            load_lds16(gs + q * 32768, ldst0 + q * 1024);
        __syncthreads();                                   // staging landed (vmcnt drained)

        #pragma unroll
        for (int ct = 0; ct < 2; ++ct) {                   // slot = ct (compile-time)
            const int c = it * 2 + ct;
            f32x4 acc[2][2];
            #pragma unroll
            for (int mf = 0; mf < 2; ++mf)
                #pragma unroll
                for (int f = 0; f < 2; ++f)
                    acc[mf][f] = (f32x4){0.f, 0.f, 0.f, 0.f};

            #pragma unroll
            for (int kk = 0; kk < 8; ++kk) {
                short8_t b0 = *(const short8_t*)(bbase + ct * 16384 + kk * 2048);
                short8_t b1 = *(const short8_t*)(bbase + ct * 16384 + kk * 2048 + 256);
                #pragma unroll
                for (int mf = 0; mf < 2; ++mf) {
                    acc[mf][0] = __builtin_amdgcn_mfma_f32_16x16x32_bf16(af[kk][mf], b0, acc[mf][0], 0, 0, 0);
                    acc[mf][1] = __builtin_amdgcn_mfma_f32_16x16x32_bf16(af[kk][mf], b1, acc[mf][1], 0, 0, 0);
                }
            }

            const float bx0 = bxiT[c * 32 + l15];
            const float bx1 = bxiT[c * 32 + 16 + l15];
            #pragma unroll
            for (int mf = 0; mf < 2; ++mf)
                #pragma unroll
                for (int r = 0; r < 4; ++r) {
                    float hv = hs[row0 + mf * 16 + g * 4 + r][c];
                    he[mf][0][r] += ptanh(acc[mf][0][r] + bx0) * hv;
                    he[mf][1][r] += ptanh(acc[mf][1][r] + bx1) * hv;
                }
        }
    }

    // store He (sorted order), scaled
    #pragma unroll
    for (int mf = 0; mf < 2; ++mf)
        #pragma unroll
        for (int r = 0; r < 4; ++r) {
            int el = row0 + mf * 16 + g * 4 + r;
            int ep = eb + el;
            if (ep < EE) {
                float sc = scale_s[el];
                HeB[(size_t)ep * SS + l15]      = f32_to_bf16_rne(he[mf][0][r] * sc);
                HeB[(size_t)ep * SS + 16 + l15] = f32_to_bf16_rne(he[mf][1][r] * sc);
            }
        }
}

// ---------------- K_reduce_out: H2 = H1 + segsum(He); out = log_softmax(H2@Wout+bout) ----------------
__global__ void k_reduce_out(const unsigned short* __restrict__ HeB, const int* __restrict__ rowptr,
                             const float* __restrict__ H1, const float* __restrict__ Wout,
                             const float* __restrict__ bout, float* __restrict__ out) {
    __shared__ float h2[8][33];
    __shared__ float lgS[8][10];
    __shared__ float lseS[8];
    int tid = threadIdx.x;
    int un8 = tid >> 5, s = tid & 31;
    int u = blockIdx.x * 8 + un8;
    int p0 = rowptr[u], p1 = rowptr[u + 1];
    float acc = H1[u * SS + s];
    for (int p = p0; p < p1; ++p)
        acc += bf16_to_f32(HeB[(size_t)p * SS + s]);
    h2[un8][s] = acc;
    __syncthreads();
    if (tid < 80) {
        int un = tid / 10, c = tid - un * 10;
        float a = bout[c];
        #pragma unroll
        for (int s2 = 0; s2 < SS; ++s2) a += h2[un][s2] * Wout[s2 * CC + c];
        lgS[un][c] = a;
    }
    __syncthreads();
    if (tid < 8) {
        float mx = lgS[tid][0];
        #pragma unroll
        for (int c = 1; c < CC; ++c) mx = fmaxf(mx, lgS[tid][c]);
        float se = 0.f;
        #pragma unroll
        for (int c = 0; c < CC; ++c)
            se += __builtin_amdgcn_exp2f((lgS[tid][c] - mx) * 1.4426950408889634f);
        lseS[tid] = mx + __builtin_amdgcn_logf(se) * 0.6931471805599453f;
    }
    __syncthreads();
    if (tid < 80) {
        int un = tid / 10, c = tid - un * 10;
        out[(size_t)(blockIdx.x * 8 + un) * CC + c] = lgS[un][c] - lseS[un];
    }
}

extern "C" void kernel_launch(void* const* d_in, const int* in_sizes, int n_in,
                              void* d_out, int out_size, void* d_ws, size_t ws_size,
                              hipStream_t stream) {
    const float* feat = (const float*)d_in[0];
    const int*   Xn   = (const int*)d_in[1];
    const int*   Xe   = (const int*)d_in[2];
    const float* dg   = (const float*)d_in[3];
    const float* Wxi  = (const float*)d_in[4];
    const float* bxi  = (const float*)d_in[5];
    const float* Wrou = (const float*)d_in[6];
    const float* brou = (const float*)d_in[7];
    const float* Wout = (const float*)d_in[8];
    const float* bout = (const float*)d_in[9];
    float* out = (float*)d_out;

    char* ws = (char*)d_ws;
    unsigned short* featB  = (unsigned short*)(ws);                      // 12,800,000
    unsigned short* WxiB   = (unsigned short*)(ws + 12800000);           //    524,288
    unsigned short* HeB    = (unsigned short*)(ws + 13324288);           // 12,800,000
    float*          H1     = (float*)(ws + 26124288);                    //  6,400,000
    int*            perm   = (int*)(ws + 32524288);                      //    800,000
    int*            rowptr = (int*)(ws + 33324288);                      //    200,064
    int*            cursor = (int*)(ws + 33524352);                      //    200,000
    int*            cnt    = (int*)(ws + 33724352);                      //    200,000
    float*          bxiT   = (float*)(ws + 33924352);                    //      4,096

    hipMemsetAsync(cnt, 0, 200000, stream);

    k_prep      <<<8057, 256, 0, stream>>>(feat, featB, Wxi, WxiB, bxi, bxiT, Xn, cnt);
    k_h1        <<<(VV * SS) / 256, 256, 0, stream>>>(feat, Wrou, brou, cnt, H1);
    k_scan      <<<1, 1024, 0, stream>>>(cnt, rowptr, cursor);
    k_scatter   <<<782, 256, 0, stream>>>(Xn, cursor, perm);
    k_edge_gemm <<<(EE + 127) / 128, 256, 0, stream>>>(featB, WxiB, Xn, Xe, dg, bxiT, perm, H1, HeB);
    k_reduce_out<<<VV / 8, 256, 0, stream>>>(HeB, rowptr, H1, Wout, bout, out);
}

// Round 7
// 322.409 us; speedup vs baseline: 1.3190x; 1.3190x over previous
//
#include <hip/hip_runtime.h>

// ---------------- problem constants ----------------
#define EE 200000
#define VV 50000
#define LN 128
#define KD 256     // 2*LN
#define SS 32
#define NN 1024    // SS*SS
#define CC 10
#define MUS 0.028125f   // MU/S = 0.9/32

typedef short short8_t __attribute__((ext_vector_type(8)));
typedef float f32x4 __attribute__((ext_vector_type(4)));

__device__ __forceinline__ unsigned short f32_to_bf16_rne(float f) {
    union { float f; unsigned u; } x; x.f = f;
    unsigned r = x.u + 0x7FFFu + ((x.u >> 16) & 1u);
    return (unsigned short)(r >> 16);
}

__device__ __forceinline__ float bf16_to_f32(unsigned short h) {
    union { unsigned u; float f; } x; x.u = ((unsigned)h) << 16; return x.f;
}

__device__ __forceinline__ float tanh_fast(float x) {
    float t = __builtin_amdgcn_exp2f(x * 2.885390081777927f);
    return 1.0f - 2.0f * __builtin_amdgcn_rcpf(t + 1.0f);
}

// Pade(3,2): x(27+x^2)/(27+9x^2). Validated R3/R5 (absmax 0.0156 vs 6.8e-2 thr).
__device__ __forceinline__ float ptanh(float x) {
    float x2 = x * x;
    return x * (27.f + x2) * __builtin_amdgcn_rcpf(27.f + 9.f * x2);
}

__device__ __forceinline__ void load_lds16(const void* g, void* l) {
    __builtin_amdgcn_global_load_lds(
        (const __attribute__((address_space(1))) unsigned int*)g,
        (__attribute__((address_space(3))) unsigned int*)l,
        16, 0, 0);
}

// ---------------- K_prep: feat->bf16 | Wxi->bf16 permuted | bxiT | hist ----------------
__global__ void k_prep(const float* __restrict__ feat, unsigned short* __restrict__ featB,
                       const float* __restrict__ Wxi, unsigned short* __restrict__ WxiB,
                       const float* __restrict__ bxi, float* __restrict__ bxiT,
                       const int* __restrict__ Xn, int* __restrict__ cnt) {
    int b = blockIdx.x, tid = threadIdx.x;
    if (b < 6250) {
        int idx = b * 256 + tid;                       // VV*LN/4
        float4 v = ((const float4*)feat)[idx];
        ushort4 o;
        o.x = f32_to_bf16_rne(v.x); o.y = f32_to_bf16_rne(v.y);
        o.z = f32_to_bf16_rne(v.z); o.w = f32_to_bf16_rne(v.w);
        ((ushort4*)featB)[idx] = o;
    } else if (b < 7274) {
        int idx = (b - 6250) * 256 + tid;              // KD*NN
        int k = idx >> 10, ncol = idx & 1023;
        int np = ((ncol & 31) << 5) | (ncol >> 5);     // n' = j*32+i
        WxiB[((size_t)(k >> 3) * NN + np) * 8 + (k & 7)] = f32_to_bf16_rne(Wxi[idx]);
    } else if (b == 7274) {
        #pragma unroll
        for (int it = 0; it < 4; ++it) {
            int i = it * 256 + tid;
            bxiT[i] = bxi[(i & 31) * 32 + (i >> 5)];
        }
    } else {
        int e = (b - 7275) * 256 + tid;
        if (e < EE) atomicAdd(&cnt[Xn[e]], 1);
    }
}

// ---------------- 3-kernel scan (R3-proven) ----------------
__global__ void k_scan1(const int* __restrict__ cnt, int* __restrict__ rowptr,
                        int* __restrict__ bsum) {
    __shared__ int s[256];
    int i = blockIdx.x * 256 + threadIdx.x;
    int x = (i < VV) ? cnt[i] : 0;
    s[threadIdx.x] = x; __syncthreads();
    int v = x;
    #pragma unroll
    for (int off = 1; off < 256; off <<= 1) {
        int t = (threadIdx.x >= off) ? s[threadIdx.x - off] : 0;
        __syncthreads();
        v += t; s[threadIdx.x] = v;
        __syncthreads();
    }
    if (i < VV) rowptr[i] = v - x;
    if (threadIdx.x == 255) bsum[blockIdx.x] = v;
}

__global__ void k_scan2(const int* __restrict__ bsum, int* __restrict__ boff, int nb) {
    __shared__ int s[256];
    int t = threadIdx.x;
    int x = (t < nb) ? bsum[t] : 0;
    s[t] = x; __syncthreads();
    int v = x;
    #pragma unroll
    for (int off = 1; off < 256; off <<= 1) {
        int tt = (t >= off) ? s[t - off] : 0;
        __syncthreads();
        v += tt; s[t] = v;
        __syncthreads();
    }
    boff[t] = v - x;
}

__global__ void k_scan3(int* __restrict__ rowptr, const int* __restrict__ boff,
                        int* __restrict__ cursor) {
    int i = blockIdx.x * 256 + threadIdx.x;
    if (i < VV) {
        int r = rowptr[i] + boff[blockIdx.x];
        rowptr[i] = r;
        cursor[i] = r;
    }
    if (blockIdx.x == 0 && threadIdx.x == 0) rowptr[VV] = EE;
}

__global__ void k_scatter(const int* __restrict__ Xn, int* __restrict__ cursor,
                          int* __restrict__ perm) {
    int e = blockIdx.x * 256 + threadIdx.x;
    if (e < EE) {
        int p = atomicAdd(&cursor[Xn[e]], 1);
        perm[p] = e;
    }
}

// ---------------- K_h1: H1[u] = cnt[u] * tanh(feat[u] @ Wrou + brou) ----------------
__global__ void k_h1(const float* __restrict__ feat, const float* __restrict__ Wrou,
                     const float* __restrict__ brou, const int* __restrict__ cnt,
                     float* __restrict__ H1) {
    int gid = blockIdx.x * 256 + threadIdx.x;          // VV*SS
    int u = gid >> 5, s = gid & 31;
    const float* fr = feat + (size_t)u * LN;
    float a = brou[s];
    #pragma unroll 8
    for (int k = 0; k < LN; ++k) a += fr[k] * Wrou[k * SS + s];
    H1[gid] = (float)cnt[u] * tanh_fast(a);
}

// ---------------- K4: He[e][i] = scale_e * sum_j ptanh(S[e][i,j]+bx) * h_e[j] ----------------
// wave = 32 edges x full N; B double-buffered in LDS, stage(c+1) overlaps compute(c)
__global__ void __launch_bounds__(256, 3)
k_edge_gemm(const unsigned short* __restrict__ featB, const unsigned short* __restrict__ WxiB,
            const int* __restrict__ Xn, const int* __restrict__ Xe,
            const float* __restrict__ dg, const float* __restrict__ bxiT,
            const int* __restrict__ perm, const float* __restrict__ H1,
            unsigned short* __restrict__ HeB) {
    __shared__ __align__(16) unsigned short Bs[2 * 8192];   // 2 slots x 16 KB (one chunk each)
    __shared__ float hs[128][33];                           // 16.9 KB
    __shared__ int   us[128], vs[128];
    __shared__ float scale_s[128];

    const int tid = threadIdx.x;
    const int eb = blockIdx.x * 128;

    if (tid < 128) {
        int p = eb + tid; if (p > EE - 1) p = EE - 1;
        int e0 = perm[p];
        us[tid] = Xn[e0]; vs[tid] = Xe[e0];
        scale_s[tid] = MUS / dg[e0];
    }
    __syncthreads();

    const int w = tid >> 6, lane = tid & 63;
    const int g = lane >> 4, l15 = lane & 15;
    const int row0 = w * 32;

    // A fragments, gathered once (64 VGPR)
    short8_t af[8][2];
    #pragma unroll
    for (int kk = 0; kk < 8; ++kk)
        #pragma unroll
        for (int mf = 0; mf < 2; ++mf) {
            int el = row0 + mf * 16 + l15;
            int node = (kk < 4) ? us[el] : vs[el];
            af[kk][mf] = *(const short8_t*)(featB + (size_t)node * LN + (kk & 3) * 32 + g * 8);
        }

    // stage h rows (coalesced)
    #pragma unroll
    for (int it = 0; it < 16; ++it) {
        int idx = it * 256 + tid;
        int el = idx >> 5, s = idx & 31;
        hs[el][s] = H1[us[el] * SS + s];
    }

    // staging geometry: chunk c slot data unit U = 0..1023 (= G*32 + nl), 16 B each
    // global byte = (U>>5)*16384 + c*512 + (U&31)*16 ; LDS byte = slot*16384 + U*16
    size_t qoff[4];
    int ldsoff[4];
    #pragma unroll
    for (int q = 0; q < 4; ++q) {
        int U = q * 256 + tid;
        qoff[q] = (size_t)(U >> 5) * 16384 + (size_t)(U & 31) * 16;
        ldsoff[q] = U * 16;
    }
    const char* bbase = (const char*)Bs + (g * 512 + l15 * 16);

    f32x4 he[2][2];
    #pragma unroll
    for (int mf = 0; mf < 2; ++mf)
        #pragma unroll
        for (int f = 0; f < 2; ++f)
            he[mf][f] = (f32x4){0.f, 0.f, 0.f, 0.f};

    // prologue: stage chunk 0 -> slot 0
    #pragma unroll
    for (int q = 0; q < 4; ++q)
        load_lds16((const char*)WxiB + qoff[q], (char*)Bs + ldsoff[q]);
    __syncthreads();

    #pragma unroll 1
    for (int c = 0; c < 32; ++c) {
        // stage next chunk into the other slot (overlaps with compute below)
        if (c < 31) {
            const char* gs = (const char*)WxiB + (size_t)(c + 1) * 512;
            char* ld = (char*)Bs + ((c + 1) & 1) * 16384;
            #pragma unroll
            for (int q = 0; q < 4; ++q)
                load_lds16(gs + qoff[q], ld + ldsoff[q]);
        }

        // compute chunk c from slot c&1
        const char* bslot = bbase + (c & 1) * 16384;
        f32x4 acc[2][2];
        #pragma unroll
        for (int mf = 0; mf < 2; ++mf)
            #pragma unroll
            for (int f = 0; f < 2; ++f)
                acc[mf][f] = (f32x4){0.f, 0.f, 0.f, 0.f};

        #pragma unroll
        for (int kk = 0; kk < 8; ++kk) {
            short8_t b0 = *(const short8_t*)(bslot + kk * 2048);
            short8_t b1 = *(const short8_t*)(bslot + kk * 2048 + 256);
            #pragma unroll
            for (int mf = 0; mf < 2; ++mf) {
                acc[mf][0] = __builtin_amdgcn_mfma_f32_16x16x32_bf16(af[kk][mf], b0, acc[mf][0], 0, 0, 0);
                acc[mf][1] = __builtin_amdgcn_mfma_f32_16x16x32_bf16(af[kk][mf], b1, acc[mf][1], 0, 0, 0);
            }
        }

        const float bx0 = bxiT[c * 32 + l15];
        const float bx1 = bxiT[c * 32 + 16 + l15];
        #pragma unroll
        for (int mf = 0; mf < 2; ++mf)
            #pragma unroll
            for (int r = 0; r < 4; ++r) {
                float hv = hs[row0 + mf * 16 + g * 4 + r][c];
                he[mf][0][r] += ptanh(acc[mf][0][r] + bx0) * hv;
                he[mf][1][r] += ptanh(acc[mf][1][r] + bx1) * hv;
            }

        __syncthreads();   // drains this iter's stage (latency covered by compute)
    }

    // store He (sorted order), scaled
    #pragma unroll
    for (int mf = 0; mf < 2; ++mf)
        #pragma unroll
        for (int r = 0; r < 4; ++r) {
            int el = row0 + mf * 16 + g * 4 + r;
            int ep = eb + el;
            if (ep < EE) {
                float sc = scale_s[el];
                HeB[(size_t)ep * SS + l15]      = f32_to_bf16_rne(he[mf][0][r] * sc);
                HeB[(size_t)ep * SS + 16 + l15] = f32_to_bf16_rne(he[mf][1][r] * sc);
            }
        }
}

// ---------------- K_reduce_out: H2 = H1 + segsum(He); out = log_softmax(H2@Wout+bout) ----------------
__global__ void k_reduce_out(const unsigned short* __restrict__ HeB, const int* __restrict__ rowptr,
                             const float* __restrict__ H1, const float* __restrict__ Wout,
                             const float* __restrict__ bout, float* __restrict__ out) {
    __shared__ float h2[8][33];
    __shared__ float lgS[8][10];
    __shared__ float lseS[8];
    int tid = threadIdx.x;
    int un8 = tid >> 5, s = tid & 31;
    int u = blockIdx.x * 8 + un8;
    int p0 = rowptr[u], p1 = rowptr[u + 1];
    float acc = H1[u * SS + s];
    for (int p = p0; p < p1; ++p)
        acc += bf16_to_f32(HeB[(size_t)p * SS + s]);
    h2[un8][s] = acc;
    __syncthreads();
    if (tid < 80) {
        int un = tid / 10, c = tid - un * 10;
        float a = bout[c];
        #pragma unroll
        for (int s2 = 0; s2 < SS; ++s2) a += h2[un][s2] * Wout[s2 * CC + c];
        lgS[un][c] = a;
    }
    __syncthreads();
    if (tid < 8) {
        float mx = lgS[tid][0];
        #pragma unroll
        for (int c = 1; c < CC; ++c) mx = fmaxf(mx, lgS[tid][c]);
        float se = 0.f;
        #pragma unroll
        for (int c = 0; c < CC; ++c)
            se += __builtin_amdgcn_exp2f((lgS[tid][c] - mx) * 1.4426950408889634f);
        lseS[tid] = mx + __builtin_amdgcn_logf(se) * 0.6931471805599453f;
    }
    __syncthreads();
    if (tid < 80) {
        int un = tid / 10, c = tid - un * 10;
        out[(size_t)(blockIdx.x * 8 + un) * CC + c] = lgS[un][c] - lseS[un];
    }
}

extern "C" void kernel_launch(void* const* d_in, const int* in_sizes, int n_in,
                              void* d_out, int out_size, void* d_ws, size_t ws_size,
                              hipStream_t stream) {
    const float* feat = (const float*)d_in[0];
    const int*   Xn   = (const int*)d_in[1];
    const int*   Xe   = (const int*)d_in[2];
    const float* dg   = (const float*)d_in[3];
    const float* Wxi  = (const float*)d_in[4];
    const float* bxi  = (const float*)d_in[5];
    const float* Wrou = (const float*)d_in[6];
    const float* brou = (const float*)d_in[7];
    const float* Wout = (const float*)d_in[8];
    const float* bout = (const float*)d_in[9];
    float* out = (float*)d_out;

    char* ws = (char*)d_ws;
    unsigned short* featB  = (unsigned short*)(ws);                      // 12,800,000
    unsigned short* WxiB   = (unsigned short*)(ws + 12800000);           //    524,288
    unsigned short* HeB    = (unsigned short*)(ws + 13324288);           // 12,800,000
    float*          H1     = (float*)(ws + 26124288);                    //  6,400,000
    int*            perm   = (int*)(ws + 32524288);                      //    800,000
    int*            rowptr = (int*)(ws + 33324288);                      //    200,064
    int*            cursor = (int*)(ws + 33524352);                      //    200,000
    int*            cnt    = (int*)(ws + 33724352);                      //    200,000
    float*          bxiT   = (float*)(ws + 33924352);                    //      4,096
    int*            bsum   = (int*)(ws + 33928448);                      //      1,024
    int*            boff   = (int*)(ws + 33929472);                      //      1,024

    hipMemsetAsync(cnt, 0, 200000, stream);

    k_prep      <<<8057, 256, 0, stream>>>(feat, featB, Wxi, WxiB, bxi, bxiT, Xn, cnt);
    k_h1        <<<(VV * SS) / 256, 256, 0, stream>>>(feat, Wrou, brou, cnt, H1);
    k_scan1     <<<196, 256, 0, stream>>>(cnt, rowptr, bsum);
    k_scan2     <<<1, 256, 0, stream>>>(bsum, boff, 196);
    k_scan3     <<<196, 256, 0, stream>>>(rowptr, boff, cursor);
    k_scatter   <<<782, 256, 0, stream>>>(Xn, cursor, perm);
    k_edge_gemm <<<(EE + 127) / 128, 256, 0, stream>>>(featB, WxiB, Xn, Xe, dg, bxiT, perm, H1, HeB);
    k_reduce_out<<<VV / 8, 256, 0, stream>>>(HeB, rowptr, H1, Wout, bout, out);
}

// Round 8
// 319.697 us; speedup vs baseline: 1.3302x; 1.0085x over previous
//
#include <hip/hip_runtime.h>

// ---------------- problem constants ----------------
#define EE 200000
#define VV 50000
#define LN 128
#define KD 256     // 2*LN
#define SS 32
#define NN 1024    // SS*SS
#define CC 10
#define MUS 0.028125f   // MU/S = 0.9/32

typedef short short8_t __attribute__((ext_vector_type(8)));
typedef float f32x4 __attribute__((ext_vector_type(4)));

__device__ __forceinline__ unsigned short f32_to_bf16_rne(float f) {
    union { float f; unsigned u; } x; x.f = f;
    unsigned r = x.u + 0x7FFFu + ((x.u >> 16) & 1u);
    return (unsigned short)(r >> 16);
}

__device__ __forceinline__ float bf16_to_f32(unsigned short h) {
    union { unsigned u; float f; } x; x.u = ((unsigned)h) << 16; return x.f;
}

__device__ __forceinline__ float tanh_fast(float x) {
    float t = __builtin_amdgcn_exp2f(x * 2.885390081777927f);
    return 1.0f - 2.0f * __builtin_amdgcn_rcpf(t + 1.0f);
}

// Pade(3,2): validated R3/R5/R7 (absmax 0.0156 vs 6.8e-2 thr).
__device__ __forceinline__ float ptanh(float x) {
    float x2 = x * x;
    return x * (27.f + x2) * __builtin_amdgcn_rcpf(27.f + 9.f * x2);
}

__device__ __forceinline__ void load_lds16(const void* g, void* l) {
    __builtin_amdgcn_global_load_lds(
        (const __attribute__((address_space(1))) unsigned int*)g,
        (__attribute__((address_space(3))) unsigned int*)l,
        16, 0, 0);
}

// ---------------- K_prep: featB | WxiB | bxiT | hist | R ----------------
// [0,6250) featB ; [6250,7274) WxiB ; 7274 bxiT ; [7275,8057) hist ; [8057,14307) R
__global__ void k_prep(const float* __restrict__ feat, unsigned short* __restrict__ featB,
                       const float* __restrict__ Wxi, unsigned short* __restrict__ WxiB,
                       const float* __restrict__ bxi, float* __restrict__ bxiT,
                       const int* __restrict__ Xn, int* __restrict__ cnt,
                       const float* __restrict__ Wrou, const float* __restrict__ brou,
                       float* __restrict__ R) {
    int b = blockIdx.x, tid = threadIdx.x;
    if (b < 6250) {
        int idx = b * 256 + tid;                       // VV*LN/4
        float4 v = ((const float4*)feat)[idx];
        ushort4 o;
        o.x = f32_to_bf16_rne(v.x); o.y = f32_to_bf16_rne(v.y);
        o.z = f32_to_bf16_rne(v.z); o.w = f32_to_bf16_rne(v.w);
        ((ushort4*)featB)[idx] = o;
    } else if (b < 7274) {
        int idx = (b - 6250) * 256 + tid;              // KD*NN
        int k = idx >> 10, ncol = idx & 1023;
        int np = ((ncol & 31) << 5) | (ncol >> 5);     // n' = j*32+i
        WxiB[((size_t)(k >> 3) * NN + np) * 8 + (k & 7)] = f32_to_bf16_rne(Wxi[idx]);
    } else if (b == 7274) {
        #pragma unroll
        for (int it = 0; it < 4; ++it) {
            int i = it * 256 + tid;
            bxiT[i] = bxi[(i & 31) * 32 + (i >> 5)];
        }
    } else if (b < 8057) {
        int e = (b - 7275) * 256 + tid;
        if (e < EE) atomicAdd(&cnt[Xn[e]], 1);
    } else {
        int gid = (b - 8057) * 256 + tid;              // VV*SS
        int u = gid >> 5, s = gid & 31;
        const float* fr = feat + (size_t)u * LN;
        float a = brou[s];
        #pragma unroll 8
        for (int k = 0; k < LN; ++k) a += fr[k] * Wrou[k * SS + s];
        R[gid] = tanh_fast(a);
    }
}

// ---------------- K_scan_lb: single-pass decoupled-lookback exclusive scan ----------------
// 196 blocks (<=256 CUs -> co-resident). flags[b] = state|value: bit31=P, bit30=A.
__global__ void __launch_bounds__(256) k_scan_lb(const int* __restrict__ cnt,
                                                 int* __restrict__ rowptr,
                                                 int* __restrict__ cursor,
                                                 unsigned int* flags) {
    __shared__ int s[256];
    __shared__ int bp;
    int b = blockIdx.x, tid = threadIdx.x;
    int i = b * 256 + tid;
    int x = (i < VV) ? cnt[i] : 0;
    s[tid] = x; __syncthreads();
    int v = x;
    #pragma unroll
    for (int off = 1; off < 256; off <<= 1) {
        int t = (tid >= off) ? s[tid - off] : 0;
        __syncthreads();
        v += t; s[tid] = v;
        __syncthreads();
    }
    int agg = s[255];

    if (b == 0) {
        if (tid == 0) {
            bp = 0;
            atomicExch(&flags[0], 0x80000000u | (unsigned)agg);   // publish P
        }
    } else {
        if (tid == 0)
            atomicExch(&flags[b], 0x40000000u | (unsigned)agg);   // publish A
        if (tid < 64) {
            int lane = tid;
            int base = b - 1;
            int pref = 0;
            while (true) {
                int idx = base - lane;
                unsigned wv;
                if (idx >= 0) {
                    do { wv = atomicAdd(&flags[idx], 0u); } while ((wv & 0xC0000000u) == 0u);
                } else {
                    wv = 0x80000000u;                              // virtual P=0
                }
                bool isP = (wv >= 0x80000000u);
                unsigned long long bal = __ballot(isP);
                int Lp = bal ? __builtin_ctzll(bal) : 64;          // nearest P lane
                int val = (int)(wv & 0x3FFFFFFFu);
                int contrib = (lane < Lp) ? val : ((lane == Lp && bal) ? val : 0);
                #pragma unroll
                for (int o = 1; o < 64; o <<= 1) contrib += __shfl_xor(contrib, o);
                pref += contrib;
                if (bal) break;
                base -= 64;
            }
            if (lane == 0) {
                bp = pref;
                atomicExch(&flags[b], 0x80000000u | (unsigned)(pref + agg));  // publish P
            }
        }
    }
    __syncthreads();
    int excl = v - x + bp;
    if (i < VV) { rowptr[i] = excl; cursor[i] = excl; }
    if (b == 0 && tid == 0) rowptr[VV] = EE;
}

__global__ void k_scatter(const int* __restrict__ Xn, int* __restrict__ cursor,
                          int* __restrict__ perm) {
    int e = blockIdx.x * 256 + threadIdx.x;
    if (e < EE) {
        int p = atomicAdd(&cursor[Xn[e]], 1);
        perm[p] = e;
    }
}

// ---------------- K4: He[e][i] = scale_e * sum_j ptanh(S[e][i,j]+bx) * h_e[j] ----------------
// wave = 64 edges x full N; B double-buffered, counted-drain AFTER compute (bare s_barrier)
__global__ void __launch_bounds__(256, 2)
k_edge_gemm(const unsigned short* __restrict__ featB, const unsigned short* __restrict__ WxiB,
            const int* __restrict__ Xn, const int* __restrict__ Xe,
            const float* __restrict__ dg, const float* __restrict__ bxiT,
            const int* __restrict__ perm, const float* __restrict__ R,
            const int* __restrict__ rowptr, unsigned short* __restrict__ HeB) {
    __shared__ __align__(16) unsigned short Bs[2 * 8192];   // 2 slots x 16 KB
    __shared__ float hs[256][33];                           // 33.8 KB
    __shared__ int   us[256], vs[256];
    __shared__ float scale_s[256], cs[256];

    const int tid = threadIdx.x;
    const int eb = blockIdx.x * 256;

    {
        int p = eb + tid; if (p > EE - 1) p = EE - 1;
        int e0 = perm[p];
        int u = Xn[e0];
        us[tid] = u; vs[tid] = Xe[e0];
        scale_s[tid] = MUS / dg[e0];
        cs[tid] = (float)(rowptr[u + 1] - rowptr[u]);
    }
    __syncthreads();

    const int w = tid >> 6, lane = tid & 63;
    const int g = lane >> 4, l15 = lane & 15;
    const int row0 = w * 64;

    // A fragments for 64 edges (128 VGPR)
    short8_t af[8][4];
    #pragma unroll
    for (int kk = 0; kk < 8; ++kk)
        #pragma unroll
        for (int mf = 0; mf < 4; ++mf) {
            int el = row0 + mf * 16 + l15;
            int node = (kk < 4) ? us[el] : vs[el];
            af[kk][mf] = *(const short8_t*)(featB + (size_t)node * LN + (kk & 3) * 32 + g * 8);
        }

    // stage h rows: hs[el][s] = cnt[u]*R[u][s]
    #pragma unroll
    for (int it = 0; it < 32; ++it) {
        int idx = it * 256 + tid;
        int el = idx >> 5, s2 = idx & 31;
        hs[el][s2] = cs[el] * R[us[el] * SS + s2];
    }

    // staging geometry (validated R5/R7): unit U = q*256+tid
    size_t qoff[4];
    int ldsoff[4];
    #pragma unroll
    for (int q = 0; q < 4; ++q) {
        int U = q * 256 + tid;
        qoff[q] = (size_t)(U >> 5) * 16384 + (size_t)(U & 31) * 16;
        ldsoff[q] = U * 16;
    }
    const char* bbase = (const char*)Bs + (g * 512 + l15 * 16);

    f32x4 he[4][2];
    #pragma unroll
    for (int mf = 0; mf < 4; ++mf)
        #pragma unroll
        for (int f = 0; f < 2; ++f)
            he[mf][f] = (f32x4){0.f, 0.f, 0.f, 0.f};

    // prologue: stage chunk 0 -> slot 0 (syncthreads also publishes hs)
    #pragma unroll
    for (int q = 0; q < 4; ++q)
        load_lds16((const char*)WxiB + qoff[q], (char*)Bs + ldsoff[q]);
    __syncthreads();

    #pragma unroll 1
    for (int c = 0; c < 32; ++c) {
        // issue next-chunk stage FIRST (flight hidden under compute below)
        if (c < 31) {
            const char* gs = (const char*)WxiB + (size_t)(c + 1) * 512;
            char* ld = (char*)Bs + ((c + 1) & 1) * 16384;
            #pragma unroll
            for (int q = 0; q < 4; ++q)
                load_lds16(gs + qoff[q], ld + ldsoff[q]);
        }

        const char* bslot = bbase + (c & 1) * 16384;
        f32x4 acc[4][2];
        #pragma unroll
        for (int mf = 0; mf < 4; ++mf)
            #pragma unroll
            for (int f = 0; f < 2; ++f)
                acc[mf][f] = (f32x4){0.f, 0.f, 0.f, 0.f};

        #pragma unroll
        for (int kk = 0; kk < 8; ++kk) {
            short8_t b0 = *(const short8_t*)(bslot + kk * 2048);
            short8_t b1 = *(const short8_t*)(bslot + kk * 2048 + 256);
            #pragma unroll
            for (int mf = 0; mf < 4; ++mf) {
                acc[mf][0] = __builtin_amdgcn_mfma_f32_16x16x32_bf16(af[kk][mf], b0, acc[mf][0], 0, 0, 0);
                acc[mf][1] = __builtin_amdgcn_mfma_f32_16x16x32_bf16(af[kk][mf], b1, acc[mf][1], 0, 0, 0);
            }
        }

        const float bx0 = bxiT[c * 32 + l15];
        const float bx1 = bxiT[c * 32 + 16 + l15];
        #pragma unroll
        for (int mf = 0; mf < 4; ++mf)
            #pragma unroll
            for (int r = 0; r < 4; ++r) {
                float hv = hs[row0 + mf * 16 + g * 4 + r][c];
                he[mf][0][r] += ptanh(acc[mf][0][r] + bx0) * hv;
                he[mf][1][r] += ptanh(acc[mf][1][r] + bx1) * hv;
            }

        // drain AFTER compute: stage(c+1) had the whole chunk to land -> ~free
        asm volatile("s_waitcnt vmcnt(0)" ::: "memory");
        __builtin_amdgcn_s_barrier();
        __builtin_amdgcn_sched_barrier(0);
    }

    // store He (sorted order), scaled
    #pragma unroll
    for (int mf = 0; mf < 4; ++mf)
        #pragma unroll
        for (int r = 0; r < 4; ++r) {
            int el = row0 + mf * 16 + g * 4 + r;
            int ep = eb + el;
            if (ep < EE) {
                float sc = scale_s[el];
                HeB[(size_t)ep * SS + l15]      = f32_to_bf16_rne(he[mf][0][r] * sc);
                HeB[(size_t)ep * SS + 16 + l15] = f32_to_bf16_rne(he[mf][1][r] * sc);
            }
        }
}

// ---------------- K_reduce_out: H2 = cnt*R + segsum(He); out = log_softmax(H2@Wout+bout) ----------------
__global__ void k_reduce_out(const unsigned short* __restrict__ HeB, const int* __restrict__ rowptr,
                             const float* __restrict__ R, const float* __restrict__ Wout,
                             const float* __restrict__ bout, float* __restrict__ out) {
    __shared__ float h2[8][33];
    __shared__ float lgS[8][10];
    __shared__ float lseS[8];
    int tid = threadIdx.x;
    int un8 = tid >> 5, s = tid & 31;
    int u = blockIdx.x * 8 + un8;
    int p0 = rowptr[u], p1 = rowptr[u + 1];
    float acc = (float)(p1 - p0) * R[u * SS + s];
    for (int p = p0; p < p1; ++p)
        acc += bf16_to_f32(HeB[(size_t)p * SS + s]);
    h2[un8][s] = acc;
    __syncthreads();
    if (tid < 80) {
        int un = tid / 10, c = tid - un * 10;
        float a = bout[c];
        #pragma unroll
        for (int s2 = 0; s2 < SS; ++s2) a += h2[un][s2] * Wout[s2 * CC + c];
        lgS[un][c] = a;
    }
    __syncthreads();
    if (tid < 8) {
        float mx = lgS[tid][0];
        #pragma unroll
        for (int c = 1; c < CC; ++c) mx = fmaxf(mx, lgS[tid][c]);
        float se = 0.f;
        #pragma unroll
        for (int c = 0; c < CC; ++c)
            se += __builtin_amdgcn_exp2f((lgS[tid][c] - mx) * 1.4426950408889634f);
        lseS[tid] = mx + __builtin_amdgcn_logf(se) * 0.6931471805599453f;
    }
    __syncthreads();
    if (tid < 80) {
        int un = tid / 10, c = tid - un * 10;
        out[(size_t)(blockIdx.x * 8 + un) * CC + c] = lgS[un][c] - lseS[un];
    }
}

extern "C" void kernel_launch(void* const* d_in, const int* in_sizes, int n_in,
                              void* d_out, int out_size, void* d_ws, size_t ws_size,
                              hipStream_t stream) {
    const float* feat = (const float*)d_in[0];
    const int*   Xn   = (const int*)d_in[1];
    const int*   Xe   = (const int*)d_in[2];
    const float* dg   = (const float*)d_in[3];
    const float* Wxi  = (const float*)d_in[4];
    const float* bxi  = (const float*)d_in[5];
    const float* Wrou = (const float*)d_in[6];
    const float* brou = (const float*)d_in[7];
    const float* Wout = (const float*)d_in[8];
    const float* bout = (const float*)d_in[9];
    float* out = (float*)d_out;

    char* ws = (char*)d_ws;
    unsigned short* featB  = (unsigned short*)(ws);                      // 12,800,000
    unsigned short* WxiB   = (unsigned short*)(ws + 12800000);           //    524,288
    unsigned short* HeB    = (unsigned short*)(ws + 13324288);           // 12,800,000
    float*          R      = (float*)(ws + 26124288);                    //  6,400,000
    int*            perm   = (int*)(ws + 32524288);                      //    800,000
    int*            rowptr = (int*)(ws + 33324288);                      //    200,064
    int*            cursor = (int*)(ws + 33524352);                      //    200,000
    int*            cnt    = (int*)(ws + 33724352);                      //    200,000
    unsigned int*   flags  = (unsigned int*)(ws + 33924352);             //      1,024
    float*          bxiT   = (float*)(ws + 33925376);                    //      4,096

    hipMemsetAsync(cnt, 0, 201024, stream);                              // cnt + flags

    k_prep      <<<14307, 256, 0, stream>>>(feat, featB, Wxi, WxiB, bxi, bxiT, Xn, cnt,
                                            Wrou, brou, R);
    k_scan_lb   <<<196, 256, 0, stream>>>(cnt, rowptr, cursor, flags);
    k_scatter   <<<782, 256, 0, stream>>>(Xn, cursor, perm);
    k_edge_gemm <<<782, 256, 0, stream>>>(featB, WxiB, Xn, Xe, dg, bxiT, perm, R, rowptr, HeB);
    k_reduce_out<<<VV / 8, 256, 0, stream>>>(HeB, rowptr, R, Wout, bout, out);
}

// Round 9
// 303.860 us; speedup vs baseline: 1.3995x; 1.0521x over previous
//
#include <hip/hip_runtime.h>

// ---------------- problem constants ----------------
#define EE 200000
#define VV 50000
#define LN 128
#define KD 256     // 2*LN
#define SS 32
#define NN 1024    // SS*SS
#define CC 10
#define MUS 0.028125f   // MU/S = 0.9/32

typedef short short8_t __attribute__((ext_vector_type(8)));
typedef float f32x4 __attribute__((ext_vector_type(4)));

__device__ __forceinline__ unsigned short f32_to_bf16_rne(float f) {
    union { float f; unsigned u; } x; x.f = f;
    unsigned r = x.u + 0x7FFFu + ((x.u >> 16) & 1u);
    return (unsigned short)(r >> 16);
}

__device__ __forceinline__ float bf16_to_f32(unsigned short h) {
    union { unsigned u; float f; } x; x.u = ((unsigned)h) << 16; return x.f;
}

__device__ __forceinline__ float tanh_fast(float x) {
    float t = __builtin_amdgcn_exp2f(x * 2.885390081777927f);
    return 1.0f - 2.0f * __builtin_amdgcn_rcpf(t + 1.0f);
}

// Pade(3,2): validated R3/R5/R7/R8 (absmax 0.0156 vs 6.8e-2 thr).
__device__ __forceinline__ float ptanh(float x) {
    float x2 = x * x;
    return x * (27.f + x2) * __builtin_amdgcn_rcpf(27.f + 9.f * x2);
}

__device__ __forceinline__ void load_lds16(const void* g, void* l) {
    __builtin_amdgcn_global_load_lds(
        (const __attribute__((address_space(1))) unsigned int*)g,
        (__attribute__((address_space(3))) unsigned int*)l,
        16, 0, 0);
}

// ---------------- K_prep: featB | WxiB | bxiT | hist | R ----------------
__global__ void k_prep(const float* __restrict__ feat, unsigned short* __restrict__ featB,
                       const float* __restrict__ Wxi, unsigned short* __restrict__ WxiB,
                       const float* __restrict__ bxi, float* __restrict__ bxiT,
                       const int* __restrict__ Xn, int* __restrict__ cnt,
                       const float* __restrict__ Wrou, const float* __restrict__ brou,
                       float* __restrict__ R) {
    int b = blockIdx.x, tid = threadIdx.x;
    if (b < 6250) {
        int idx = b * 256 + tid;                       // VV*LN/4
        float4 v = ((const float4*)feat)[idx];
        ushort4 o;
        o.x = f32_to_bf16_rne(v.x); o.y = f32_to_bf16_rne(v.y);
        o.z = f32_to_bf16_rne(v.z); o.w = f32_to_bf16_rne(v.w);
        ((ushort4*)featB)[idx] = o;
    } else if (b < 7274) {
        int idx = (b - 6250) * 256 + tid;              // KD*NN
        int k = idx >> 10, ncol = idx & 1023;
        int np = ((ncol & 31) << 5) | (ncol >> 5);     // n' = j*32+i
        WxiB[((size_t)(k >> 3) * NN + np) * 8 + (k & 7)] = f32_to_bf16_rne(Wxi[idx]);
    } else if (b == 7274) {
        #pragma unroll
        for (int it = 0; it < 4; ++it) {
            int i = it * 256 + tid;
            bxiT[i] = bxi[(i & 31) * 32 + (i >> 5)];
        }
    } else if (b < 8057) {
        int e = (b - 7275) * 256 + tid;
        if (e < EE) atomicAdd(&cnt[Xn[e]], 1);
    } else {
        int gid = (b - 8057) * 256 + tid;              // VV*SS
        int u = gid >> 5, s = gid & 31;
        const float* fr = feat + (size_t)u * LN;
        float a = brou[s];
        #pragma unroll 8
        for (int k = 0; k < LN; ++k) a += fr[k] * Wrou[k * SS + s];
        R[gid] = tanh_fast(a);
    }
}

// ---------------- K_scan_lb: single-pass decoupled-lookback exclusive scan ----------------
__global__ void __launch_bounds__(256) k_scan_lb(const int* __restrict__ cnt,
                                                 int* __restrict__ rowptr,
                                                 int* __restrict__ cursor,
                                                 unsigned int* flags) {
    __shared__ int s[256];
    __shared__ int bp;
    int b = blockIdx.x, tid = threadIdx.x;
    int i = b * 256 + tid;
    int x = (i < VV) ? cnt[i] : 0;
    s[tid] = x; __syncthreads();
    int v = x;
    #pragma unroll
    for (int off = 1; off < 256; off <<= 1) {
        int t = (tid >= off) ? s[tid - off] : 0;
        __syncthreads();
        v += t; s[tid] = v;
        __syncthreads();
    }
    int agg = s[255];

    if (b == 0) {
        if (tid == 0) {
            bp = 0;
            atomicExch(&flags[0], 0x80000000u | (unsigned)agg);
        }
    } else {
        if (tid == 0)
            atomicExch(&flags[b], 0x40000000u | (unsigned)agg);
        if (tid < 64) {
            int lane = tid;
            int base = b - 1;
            int pref = 0;
            while (true) {
                int idx = base - lane;
                unsigned wv;
                if (idx >= 0) {
                    do { wv = atomicAdd(&flags[idx], 0u); } while ((wv & 0xC0000000u) == 0u);
                } else {
                    wv = 0x80000000u;
                }
                bool isP = (wv >= 0x80000000u);
                unsigned long long bal = __ballot(isP);
                int Lp = bal ? __builtin_ctzll(bal) : 64;
                int val = (int)(wv & 0x3FFFFFFFu);
                int contrib = (lane < Lp) ? val : ((lane == Lp && bal) ? val : 0);
                #pragma unroll
                for (int o = 1; o < 64; o <<= 1) contrib += __shfl_xor(contrib, o);
                pref += contrib;
                if (bal) break;
                base -= 64;
            }
            if (lane == 0) {
                bp = pref;
                atomicExch(&flags[b], 0x80000000u | (unsigned)(pref + agg));
            }
        }
    }
    __syncthreads();
    int excl = v - x + bp;
    if (i < VV) { rowptr[i] = excl; cursor[i] = excl; }
    if (b == 0 && tid == 0) rowptr[VV] = EE;
}

__global__ void k_scatter(const int* __restrict__ Xn, int* __restrict__ cursor,
                          int* __restrict__ perm) {
    int e = blockIdx.x * 256 + threadIdx.x;
    if (e < EE) {
        int p = atomicAdd(&cursor[Xn[e]], 1);
        perm[p] = e;
    }
}

// ---------------- K4: He[e][i] = scale_e * sum_j ptanh(S[e][i,j]+bx) * h_e[j] ----------------
// wave = 32 edges x full N; 2-deep acc pipeline: EPI(c-1) overlaps MFMA(c)'s pipe latency.
__global__ void __launch_bounds__(256, 3)
k_edge_gemm(const unsigned short* __restrict__ featB, const unsigned short* __restrict__ WxiB,
            const int* __restrict__ Xn, const int* __restrict__ Xe,
            const float* __restrict__ dg, const float* __restrict__ bxiT,
            const int* __restrict__ perm, const float* __restrict__ R,
            const int* __restrict__ rowptr, unsigned short* __restrict__ HeB) {
    __shared__ __align__(16) unsigned short Bs[2 * 8192];   // 2 slots x 16 KB
    __shared__ float hs[128][33];                           // 16.9 KB
    __shared__ int   us[128], vs[128];
    __shared__ float scale_s[128];                          // LDS total 51,200 B -> 3 blocks/CU

    const int tid = threadIdx.x;
    const int eb = blockIdx.x * 128;

    // staging address bases (2 regs; per-q offsets are compile-time immediates)
    const size_t qbase = (size_t)((tid >> 5) * 16384 + (tid & 31) * 16);
    const int    dbase = tid * 16;

#define STAGE_CH(cc, slot) { \
    const char* gs_ = (const char*)WxiB + (size_t)((cc) * 512) + qbase; \
    char* ld_ = (char*)Bs + (slot) * 16384 + dbase; \
    load_lds16(gs_,          ld_); \
    load_lds16(gs_ + 131072, ld_ + 4096); \
    load_lds16(gs_ + 262144, ld_ + 8192); \
    load_lds16(gs_ + 393216, ld_ + 12288); }

    // stage chunk 0 immediately (critical path)
    STAGE_CH(0, 0);

    if (tid < 128) {
        int p = eb + tid; if (p > EE - 1) p = EE - 1;
        int e0 = perm[p];
        int u = Xn[e0];
        us[tid] = u; vs[tid] = Xe[e0];
        scale_s[tid] = MUS / dg[e0];
    }
    __syncthreads();

    const int w = tid >> 6, lane = tid & 63;
    const int g = lane >> 4, l15 = lane & 15;
    const int row0 = w * 32;

    // A fragments for 32 edges (64 regs)
    short8_t af[8][2];
    #pragma unroll
    for (int kk = 0; kk < 8; ++kk)
        #pragma unroll
        for (int mf = 0; mf < 2; ++mf) {
            int el = row0 + mf * 16 + l15;
            int node = (kk < 4) ? us[el] : vs[el];
            af[kk][mf] = *(const short8_t*)(featB + (size_t)node * LN + (kk & 3) * 32 + g * 8);
        }

    // stage h rows: hs[el][s] = cnt[u]*R[u][s]
    #pragma unroll
    for (int it = 0; it < 16; ++it) {
        int idx = it * 256 + tid;
        int el = idx >> 5, s2 = idx & 31;
        int u = us[el];
        float cnt = (float)(rowptr[u + 1] - rowptr[u]);
        hs[el][s2] = cnt * R[u * SS + s2];
    }
    __syncthreads();   // drains stage(0) + publishes hs

    const char* bbase = (const char*)Bs + (g * 512 + l15 * 16);
    const f32x4 z4 = {0.f, 0.f, 0.f, 0.f};
    f32x4 accA[2][2], accB[2][2], he[2][2];
    #pragma unroll
    for (int mf = 0; mf < 2; ++mf)
        #pragma unroll
        for (int f = 0; f < 2; ++f) he[mf][f] = z4;

#define MFMA_CH(slot, cur) { \
    const char* bs_ = bbase + (slot) * 16384; \
    _Pragma("unroll") \
    for (int kk = 0; kk < 8; ++kk) { \
        short8_t b0 = *(const short8_t*)(bs_ + kk * 2048); \
        short8_t b1 = *(const short8_t*)(bs_ + kk * 2048 + 256); \
        _Pragma("unroll") \
        for (int mf = 0; mf < 2; ++mf) { \
            cur[mf][0] = __builtin_amdgcn_mfma_f32_16x16x32_bf16(af[kk][mf], b0, kk ? cur[mf][0] : z4, 0, 0, 0); \
            cur[mf][1] = __builtin_amdgcn_mfma_f32_16x16x32_bf16(af[kk][mf], b1, kk ? cur[mf][1] : z4, 0, 0, 0); } } }

#define EPI_CH(j, prev) { \
    float bx0 = bxiT[(j) * 32 + l15]; \
    float bx1 = bxiT[(j) * 32 + 16 + l15]; \
    _Pragma("unroll") \
    for (int mf = 0; mf < 2; ++mf) \
        _Pragma("unroll") \
        for (int r = 0; r < 4; ++r) { \
            float hv = hs[row0 + mf * 16 + g * 4 + r][j]; \
            he[mf][0][r] += ptanh(prev[mf][0][r] + bx0) * hv; \
            he[mf][1][r] += ptanh(prev[mf][1][r] + bx1) * hv; } }

#define SYNCPT() { \
    asm volatile("s_waitcnt vmcnt(0)" ::: "memory"); \
    __builtin_amdgcn_s_barrier(); \
    __builtin_amdgcn_sched_barrier(0); }

    #pragma unroll 1
    for (int c = 0; c < 32; c += 2) {
        STAGE_CH(c + 1, 1);          // stage odd chunk -> slot1
        MFMA_CH(0, accA);            // chunk c from slot0
        if (c) EPI_CH(c - 1, accB);  // finish previous odd chunk (VALU || matrix pipe)
        SYNCPT();                    // stage(c+1) landed; slot0 reads done everywhere

        if (c + 2 < 32) STAGE_CH(c + 2, 0);   // stage next even chunk -> slot0
        MFMA_CH(1, accB);            // chunk c+1 from slot1
        EPI_CH(c, accA);             // finish chunk c
        SYNCPT();
    }
    EPI_CH(31, accB);

    // store He (sorted order), scaled
    #pragma unroll
    for (int mf = 0; mf < 2; ++mf)
        #pragma unroll
        for (int r = 0; r < 4; ++r) {
            int el = row0 + mf * 16 + g * 4 + r;
            int ep = eb + el;
            if (ep < EE) {
                float sc = scale_s[el];
                HeB[(size_t)ep * SS + l15]      = f32_to_bf16_rne(he[mf][0][r] * sc);
                HeB[(size_t)ep * SS + 16 + l15] = f32_to_bf16_rne(he[mf][1][r] * sc);
            }
        }
#undef STAGE_CH
#undef MFMA_CH
#undef EPI_CH
#undef SYNCPT
}

// ---------------- K_reduce_out: H2 = cnt*R + segsum(He); out = log_softmax(H2@Wout+bout) ----------------
__global__ void k_reduce_out(const unsigned short* __restrict__ HeB, const int* __restrict__ rowptr,
                             const float* __restrict__ R, const float* __restrict__ Wout,
                             const float* __restrict__ bout, float* __restrict__ out) {
    __shared__ float h2[8][33];
    __shared__ float lgS[8][10];
    __shared__ float lseS[8];
    int tid = threadIdx.x;
    int un8 = tid >> 5, s = tid & 31;
    int u = blockIdx.x * 8 + un8;
    int p0 = rowptr[u], p1 = rowptr[u + 1];
    float acc = (float)(p1 - p0) * R[u * SS + s];
    for (int p = p0; p < p1; ++p)
        acc += bf16_to_f32(HeB[(size_t)p * SS + s]);
    h2[un8][s] = acc;
    __syncthreads();
    if (tid < 80) {
        int un = tid / 10, c = tid - un * 10;
        float a = bout[c];
        #pragma unroll
        for (int s2 = 0; s2 < SS; ++s2) a += h2[un][s2] * Wout[s2 * CC + c];
        lgS[un][c] = a;
    }
    __syncthreads();
    if (tid < 8) {
        float mx = lgS[tid][0];
        #pragma unroll
        for (int c = 1; c < CC; ++c) mx = fmaxf(mx, lgS[tid][c]);
        float se = 0.f;
        #pragma unroll
        for (int c = 0; c < CC; ++c)
            se += __builtin_amdgcn_exp2f((lgS[tid][c] - mx) * 1.4426950408889634f);
        lseS[tid] = mx + __builtin_amdgcn_logf(se) * 0.6931471805599453f;
    }
    __syncthreads();
    if (tid < 80) {
        int un = tid / 10, c = tid - un * 10;
        out[(size_t)(blockIdx.x * 8 + un) * CC + c] = lgS[un][c] - lseS[un];
    }
}

extern "C" void kernel_launch(void* const* d_in, const int* in_sizes, int n_in,
                              void* d_out, int out_size, void* d_ws, size_t ws_size,
                              hipStream_t stream) {
    const float* feat = (const float*)d_in[0];
    const int*   Xn   = (const int*)d_in[1];
    const int*   Xe   = (const int*)d_in[2];
    const float* dg   = (const float*)d_in[3];
    const float* Wxi  = (const float*)d_in[4];
    const float* bxi  = (const float*)d_in[5];
    const float* Wrou = (const float*)d_in[6];
    const float* brou = (const float*)d_in[7];
    const float* Wout = (const float*)d_in[8];
    const float* bout = (const float*)d_in[9];
    float* out = (float*)d_out;

    char* ws = (char*)d_ws;
    unsigned short* featB  = (unsigned short*)(ws);                      // 12,800,000
    unsigned short* WxiB   = (unsigned short*)(ws + 12800000);           //    524,288
    unsigned short* HeB    = (unsigned short*)(ws + 13324288);           // 12,800,000
    float*          R      = (float*)(ws + 26124288);                    //  6,400,000
    int*            perm   = (int*)(ws + 32524288);                      //    800,000
    int*            rowptr = (int*)(ws + 33324288);                      //    200,064
    int*            cursor = (int*)(ws + 33524352);                      //    200,000
    int*            cnt    = (int*)(ws + 33724352);                      //    200,000
    unsigned int*   flags  = (unsigned int*)(ws + 33924352);             //      1,024
    float*          bxiT   = (float*)(ws + 33925376);                    //      4,096

    hipMemsetAsync(cnt, 0, 201024, stream);                              // cnt + flags

    k_prep      <<<14307, 256, 0, stream>>>(feat, featB, Wxi, WxiB, bxi, bxiT, Xn, cnt,
                                            Wrou, brou, R);
    k_scan_lb   <<<196, 256, 0, stream>>>(cnt, rowptr, cursor, flags);
    k_scatter   <<<782, 256, 0, stream>>>(Xn, cursor, perm);
    k_edge_gemm <<<(EE + 127) / 128, 256, 0, stream>>>(featB, WxiB, Xn, Xe, dg, bxiT, perm, R, rowptr, HeB);
    k_reduce_out<<<VV / 8, 256, 0, stream>>>(HeB, rowptr, R, Wout, bout, out);
}